// Round 10
// baseline (50.938 us; speedup 1.0000x reference)
//
#include <hip/hip_runtime.h>
#include <stdint.h>

#define R_NUM 4096
#define D_DIM 64
#define DEG_N 6
#define MF 8
#define GRID 256                 // one persistent block per CU
#define NR (R_NUM / GRID)        // 16 regions per wave
#define FB_COEF 0.035355339059327376f  // FB_ALPHA * FB_SCALE = 0.1/sqrt(8)

typedef float f4v __attribute__((ext_vector_type(4)));

// R10: wave-decorrelated static balance on top of R9's mask-skip pipeline.
// R9's straggler tail: all 16 waves of a block shared the same 16 regions,
// so per-CU active-edge work ~ Binomial(96,0.5) (sigma/mu 10%, max over 256
// CUs ~ +28%). Waves are fully independent (no LDS/barriers), so wave w of
// block b now owns slice w (rows 4w..4w+3) of regions ((b+16w)%256)+256*i:
// a bijective re-tiling that makes each CU's work a sum over 256
// independent regions -> sigma/mu ~2.6%, tail ~+7%. No atomics, no sync;
// per-edge-slice loads remain wave-contiguous 1KB nontemporal bursts.
// Mask skip: w_edge = mask[src]*(1+a*b), mask ~ Bernoulli(0.5) -> ~half the
// W panels are never fetched (wave-uniform exec-skip). Output stores stay
// unconditional (harness poisons d_out).
__launch_bounds__(1024, 4)
__global__ void router_kernel(const float* __restrict__ H,
                              const void* __restrict__ mask_raw,
                              const float* __restrict__ coords,
                              const float* __restrict__ W_edges,
                              const float* __restrict__ W_reg,
                              const float* __restrict__ beta_cos,
                              const float* __restrict__ beta_sin,
                              const int* __restrict__ src,
                              float* __restrict__ out) {
  const int r0   = blockIdx.x;
  const int t    = threadIdx.x;
  const int lane = t & 63;
  const int wid  = t >> 6;          // wave id 0..15 -> slice rows 4w..4w+3
  const int j0   = (t & 15) << 2;   // starting col of this lane's float4

  // wave's private region base: bijective over blocks for each wid
  const int rw0 = (r0 + wid * 16) & (GRID - 1);

  // ---- per-wave mask-dtype detection over the first 256 words (1 KB;
  // safe under every candidate encoding since the bool buffer is >= 4 KB).
  //  flag: 0 = 1-byte bool, 1 = int32, 2 = int64, 3 = float32
  const uint32_t* mw = (const uint32_t*)mask_raw;
  bool int01 = true, f01 = true, oddz = true, even1 = false;
#pragma unroll
  for (int i = 0; i < 4; ++i) {
    const int idx = lane + 64 * i;        // parity of idx == parity of lane
    const uint32_t v = mw[idx];
    int01 = int01 && (v <= 1u);
    f01   = f01 && (v == 0u || v == 0x3f800000u);
    if (lane & 1) oddz = oddz && (v == 0u);
    else          even1 = even1 || (v == 1u);
  }
  const bool all_int01 = (__ballot(int01) == ~0ULL);
  const bool all_f01   = (__ballot(f01)   == ~0ULL);
  const bool all_oddz  = (__ballot(!oddz) == 0ULL);
  const bool any_even1 = (__ballot(even1) != 0ULL);
  int mflag = 0;
  if (all_int01)    mflag = (all_oddz && any_even1) ? 2 : 1;
  else if (all_f01) mflag = 3;

  // ---- upfront edge weights for THIS WAVE's 16 regions: local edge ids
  // 0..95; lane covers {lane, lane+64}. li -> (it=li/6, k=li%6) ->
  // region rw0+it*GRID, edge k.
  float wa = 0.f, wb = 0.f;
  int   sa = 0,   sb = 0;
#define CALC_EDGE(li, wout, sout)                                            \
  if ((li) < DEG_N * NR) {                                                   \
    const int it = (li) / DEG_N;                                             \
    const int k  = (li) % DEG_N;                                             \
    const int rr = rw0 + it * GRID;                                          \
    const int e  = rr * DEG_N + k;                                           \
    const int s  = src[e];                                                   \
    sout = s;                                                                \
    const float dx = coords[2 * rr]     - coords[2 * s];                     \
    const float dy = coords[2 * rr + 1] - coords[2 * s + 1];                 \
    float b = 0.f;                                                           \
    _Pragma("unroll") for (int m = 0; m < MF; ++m) {                         \
      const float S = dx * W_reg[2 * m] + dy * W_reg[2 * m + 1];             \
      float sv, cv;                                                          \
      __sincosf(S, &sv, &cv);                                                \
      b += cv * beta_cos[m] + sv * beta_sin[m];                              \
    }                                                                        \
    bool mv;                                                                 \
    if (mflag == 1)      mv = ((const int*)mask_raw)[s] != 0;                \
    else if (mflag == 2) mv = ((const long long*)mask_raw)[s] != 0;          \
    else if (mflag == 3) mv = ((const float*)mask_raw)[s] != 0.f;            \
    else                 mv = ((const uint8_t*)mask_raw)[s] != 0;            \
    wout = mv ? fmaf(FB_COEF, b, 1.0f) : 0.f;                                \
  }
  CALC_EDGE(lane,      wa, sa)
  CALC_EDGE(lane + 64, wb, sb)
#undef CALC_EDGE

  // e is compile-time static at every use site -> wa/wb select and shfl
  // source lane are static.
#define UNPACK(itc, wout, sout)                                              \
  _Pragma("unroll") for (int k = 0; k < DEG_N; ++k) {                        \
    const int e = (itc) * DEG_N + k;                                         \
    wout[k] = __shfl(e < 64 ? wa : wb, e & 63);                              \
    sout[k] = __shfl(e < 64 ? sa : sb, e & 63);                              \
  }

  const size_t PANEL = (size_t)DEG_N * D_DIM * D_DIM;
  // this wave's byte offset inside a panel's edge-matrix: slice rows
  // 4*wid..4*wid+3, lane's float4 within them.
  const int sliceoff = t * 4;   // == wid*256 + lane*4 floats

  // ---- preload region rw0's W slice (active edges only) ----
  float cw[DEG_N]; int cs[DEG_N];
  UNPACK(0, cw, cs)
  f4v cur[DEG_N], nxt[DEG_N];
#pragma unroll
  for (int k = 0; k < DEG_N; ++k) { cur[k] = (f4v)(0.f); nxt[k] = (f4v)(0.f); }
  {
    const float* __restrict__ Wp = W_edges + (size_t)rw0 * PANEL;
#pragma unroll
    for (int k = 0; k < DEG_N; ++k)
      if (cw[k] != 0.f)
        cur[k] = __builtin_nontemporal_load(
            reinterpret_cast<const f4v*>(Wp + k * (D_DIM * D_DIM) + sliceoff));
  }

#pragma unroll
  for (int it = 0; it < NR; ++it) {
    const int r = rw0 + it * GRID;

    // 1) issue next region's W prefetches (active edges only)
    float nw[DEG_N]; int ns[DEG_N];
#pragma unroll
    for (int k = 0; k < DEG_N; ++k) { nw[k] = 0.f; ns[k] = 0; }
    if (it + 1 < NR) {
      UNPACK(it + 1, nw, ns)
      const float* __restrict__ Wp = W_edges + (size_t)(r + GRID) * PANEL;
#pragma unroll
      for (int k = 0; k < DEG_N; ++k) {
        nxt[k] = (f4v)(0.f);
        if (nw[k] != 0.f)
          nxt[k] = __builtin_nontemporal_load(
              reinterpret_cast<const f4v*>(Wp + k * (D_DIM * D_DIM) + sliceoff));
      }
    }

    // 2) fma chain on current region (skips are wave-uniform exec branches)
    float p = 0.f;
#pragma unroll
    for (int k = 0; k < DEG_N; ++k) {
      if (cw[k] != 0.f) {
        const float4 hv =
            *reinterpret_cast<const float4*>(&H[cs[k] * D_DIM + j0]);
        p = fmaf(cw[k],
                 cur[k].x * hv.x + cur[k].y * hv.y +
                 cur[k].z * hv.z + cur[k].w * hv.w,
                 p);
      }
    }

    // 3) reduce across the 16 lanes owning each output row
#pragma unroll
    for (int off = 1; off < 16; off <<= 1) p += __shfl_xor(p, off);
    const float p0 = __shfl(p, 0);
    const float p1 = __shfl(p, 16);
    const float p2 = __shfl(p, 32);
    const float p3 = __shfl(p, 48);
    if (lane == 0) {
      *reinterpret_cast<float4*>(&out[r * D_DIM + 4 * wid]) =
          make_float4(p0, p1, p2, p3);
    }

    // 4) rotate double buffer (all indices static under full unroll)
#pragma unroll
    for (int k = 0; k < DEG_N; ++k) {
      cur[k] = nxt[k]; cw[k] = nw[k]; cs[k] = ns[k];
    }
  }
#undef UNPACK
}

extern "C" void kernel_launch(void* const* d_in, const int* in_sizes, int n_in,
                              void* d_out, int out_size, void* d_ws, size_t ws_size,
                              hipStream_t stream) {
  const float* H        = (const float*)d_in[0];
  const void*  mask     = d_in[1];
  const float* coords   = (const float*)d_in[2];
  const float* W_edges  = (const float*)d_in[3];
  const float* W_reg    = (const float*)d_in[4];
  const float* beta_cos = (const float*)d_in[5];
  const float* beta_sin = (const float*)d_in[6];
  const int*   src      = (const int*)d_in[7];
  // d_in[8] (dst) is structurally repeat(arange(R), 6); not needed.

  router_kernel<<<GRID, 1024, 0, stream>>>(H, mask, coords, W_edges, W_reg,
                                           beta_cos, beta_sin, src,
                                           (float*)d_out);
}

// Round 11
// 50.069 us; speedup vs baseline: 1.0174x; 1.0174x over previous
//
#include <hip/hip_runtime.h>
#include <stdint.h>

#define R_NUM 4096
#define D_DIM 64
#define DEG_N 6
#define MF 8
#define FB_COEF 0.035355339059327376f  // FB_ALPHA * FB_SCALE = 0.1/sqrt(8)

typedef float f4v __attribute__((ext_vector_type(4)));

// R11 = R6 block structure + R9 mask-skip, dropping persistence.
// With mask-skipped (skewed) work, static persistent assignment suffers a
// Binomial(96,0.5) straggler tail (max over 256 CUs ~ +28%). One block per
// region restores the HARDWARE dispatcher's dynamic balancing: CUs that
// draw light (skip-heavy) regions free up early and get fed more blocks;
// granularity ~1 region (~2us). Measured ramp cost of 4096 blocks ~3us
// (R6 vs R8) < measured tail cost ~11us (R9 46.2 vs ~35 floor).
//
// Block body: wave 0 computes the 6 edge weights (mask-dtype ballot +
// sincos) -> 48B LDS -> barrier (no W loads in flight: R7 lesson) -> all
// waves conditionally nt-load W slices of ACTIVE edges only (w==0 edges'
// 16KB panels are never fetched: ~403 -> ~203 MB mandatory traffic).
__launch_bounds__(1024, 8)
__global__ void router_kernel(const float* __restrict__ H,
                              const void* __restrict__ mask_raw,
                              const float* __restrict__ coords,
                              const float* __restrict__ W_edges,
                              const float* __restrict__ W_reg,
                              const float* __restrict__ beta_cos,
                              const float* __restrict__ beta_sin,
                              const int* __restrict__ src,
                              float* __restrict__ out) {
  const int r    = blockIdx.x;
  const int t    = threadIdx.x;
  const int lane = t & 63;
  const int q    = t >> 4;          // output row 0..63
  const int j0   = (t & 15) << 2;   // starting col of this lane's float4

  __shared__ float s_w[DEG_N];
  __shared__ int   s_src[DEG_N];

  if (t < 64) {  // wave 0 only: mask-dtype detection + edge weights
    //  flag: 0 = 1-byte bool, 1 = int32, 2 = int64, 3 = float32
    // (first 256 words = 1 KB, safe under every candidate encoding)
    const uint32_t* mw = (const uint32_t*)mask_raw;
    bool int01 = true, f01 = true, oddz = true, even1 = false;
#pragma unroll
    for (int i = 0; i < 4; ++i) {
      const int idx = lane + 64 * i;      // parity of idx == parity of lane
      const uint32_t v = mw[idx];
      int01 = int01 && (v <= 1u);
      f01   = f01 && (v == 0u || v == 0x3f800000u);
      if (lane & 1) oddz = oddz && (v == 0u);
      else          even1 = even1 || (v == 1u);
    }
    const bool all_int01 = (__ballot(int01) == ~0ULL);
    const bool all_f01   = (__ballot(f01)   == ~0ULL);
    const bool all_oddz  = (__ballot(!oddz) == 0ULL);
    const bool any_even1 = (__ballot(even1) != 0ULL);
    int mflag = 0;
    if (all_int01)    mflag = (all_oddz && any_even1) ? 2 : 1;
    else if (all_f01) mflag = 3;

    if (lane < DEG_N) {
      const int e = r * DEG_N + lane;
      const int s = src[e];
      const float dx = coords[2 * r]     - coords[2 * s];
      const float dy = coords[2 * r + 1] - coords[2 * s + 1];
      float b = 0.f;
#pragma unroll
      for (int m = 0; m < MF; ++m) {
        const float S = dx * W_reg[2 * m] + dy * W_reg[2 * m + 1];
        float sv, cv;
        __sincosf(S, &sv, &cv);
        b += cv * beta_cos[m] + sv * beta_sin[m];
      }
      bool mv;
      if (mflag == 1)      mv = ((const int*)mask_raw)[s] != 0;
      else if (mflag == 2) mv = ((const long long*)mask_raw)[s] != 0;
      else if (mflag == 3) mv = ((const float*)mask_raw)[s] != 0.f;
      else                 mv = ((const uint8_t*)mask_raw)[s] != 0;
      s_w[lane]   = mv ? fmaf(FB_COEF, b, 1.0f) : 0.f;
      s_src[lane] = s;
    }
  }
  __syncthreads();

  // ---- block-uniform edge params ----
  const int   s0 = s_src[0], s1 = s_src[1], s2 = s_src[2];
  const int   s3 = s_src[3], s4 = s_src[4], s5 = s_src[5];
  const float w0 = s_w[0], w1 = s_w[1], w2 = s_w[2];
  const float w3 = s_w[3], w4 = s_w[4], w5 = s_w[5];

  // ---- accumulate over ACTIVE edges only (block-uniform skips) ----
  const float* __restrict__ Wb = W_edges + (size_t)r * (DEG_N * D_DIM * D_DIM);
  float p = 0.f;
#define EDGE(kk, ss, ww)                                                     \
  if (ww != 0.f) {                                                           \
    const f4v wv = __builtin_nontemporal_load(                               \
        reinterpret_cast<const f4v*>(Wb + kk * (D_DIM * D_DIM) + t * 4));    \
    const float4 hv = *reinterpret_cast<const float4*>(&H[ss * D_DIM + j0]); \
    p = fmaf(ww, wv.x * hv.x + wv.y * hv.y + wv.z * hv.z + wv.w * hv.w, p);  \
  }
  EDGE(0, s0, w0) EDGE(1, s1, w1) EDGE(2, s2, w2)
  EDGE(3, s3, w3) EDGE(4, s4, w4) EDGE(5, s5, w5)
#undef EDGE

  // ---- reduce across the 16 lanes owning each row ----
#pragma unroll
  for (int off = 1; off < 16; off <<= 1) p += __shfl_xor(p, off);

  // lanes 0,16,32,48 of each wave hold rows 4w..4w+3; compact into one
  // float4 store from lane 0 of the wave (unconditional: d_out is poisoned).
  const float p0 = __shfl(p, 0);
  const float p1 = __shfl(p, 16);
  const float p2 = __shfl(p, 32);
  const float p3 = __shfl(p, 48);
  if (lane == 0) {
    *reinterpret_cast<float4*>(&out[r * D_DIM + (q & ~3)]) =
        make_float4(p0, p1, p2, p3);
  }
}

extern "C" void kernel_launch(void* const* d_in, const int* in_sizes, int n_in,
                              void* d_out, int out_size, void* d_ws, size_t ws_size,
                              hipStream_t stream) {
  const float* H        = (const float*)d_in[0];
  const void*  mask     = d_in[1];
  const float* coords   = (const float*)d_in[2];
  const float* W_edges  = (const float*)d_in[3];
  const float* W_reg    = (const float*)d_in[4];
  const float* beta_cos = (const float*)d_in[5];
  const float* beta_sin = (const float*)d_in[6];
  const int*   src      = (const int*)d_in[7];
  // d_in[8] (dst) is structurally repeat(arange(R), 6); not needed.

  router_kernel<<<R_NUM, 1024, 0, stream>>>(H, mask, coords, W_edges, W_reg,
                                            beta_cos, beta_sin, src,
                                            (float*)d_out);
}

// Round 12
// 46.962 us; speedup vs baseline: 1.0847x; 1.0662x over previous
//
#include <hip/hip_runtime.h>
#include <stdint.h>

#define R_NUM 4096
#define D_DIM 64
#define DEG_N 6
#define MF 8
#define FB_COEF 0.035355339059327376f  // FB_ALPHA * FB_SCALE = 0.1/sqrt(8)

typedef float f4v __attribute__((ext_vector_type(4)));

// R12 = R2 barrier-free structure + R9 mask-skip + HW dynamic dispatch.
// Evidence trail: R9 (persistent static) = 46.2us, tail-bound (+28%
// Binomial(96,0.5) straggler). R10 (wave-decorrelated static) = 50.9:
// per-wave draws are WORSE. R11 (4096 blocks, wave0-prologue+barrier) =
// 50.1: barrier serializes every block's prologue. So: 4096 blocks for
// dispatcher-side dynamic balance, but NO barrier/LDS -- every wave
// computes the 6 edge weights itself (lanes 0..5 + __shfl broadcast,
// measured cost of this redundancy: ~1us chip-wide). Mask-skip: ~50% of
// edges have w==0 exactly; their 16KB W panels are never fetched
// (wave-uniform exec-skip) -> ~203 MB mandatory traffic.
__launch_bounds__(1024, 8)
__global__ void router_kernel(const float* __restrict__ H,
                              const void* __restrict__ mask_raw,
                              const float* __restrict__ coords,
                              const float* __restrict__ W_edges,
                              const float* __restrict__ W_reg,
                              const float* __restrict__ beta_cos,
                              const float* __restrict__ beta_sin,
                              const int* __restrict__ src,
                              float* __restrict__ out) {
  const int r    = blockIdx.x;
  const int t    = threadIdx.x;
  const int lane = t & 63;
  const int q    = t >> 4;          // output row 0..63
  const int j0   = (t & 15) << 2;   // starting col of this lane's float4

  // ---- per-wave mask-dtype detection over the first 256 words (1 KB;
  // safe under every candidate encoding since the bool buffer is >= 4 KB).
  //  flag: 0 = 1-byte bool, 1 = int32, 2 = int64, 3 = float32
  const uint32_t* mw = (const uint32_t*)mask_raw;
  bool int01 = true, f01 = true, oddz = true, even1 = false;
#pragma unroll
  for (int i = 0; i < 4; ++i) {
    const int idx = lane + 64 * i;        // parity of idx == parity of lane
    const uint32_t v = mw[idx];
    int01 = int01 && (v <= 1u);
    f01   = f01 && (v == 0u || v == 0x3f800000u);
    if (lane & 1) oddz = oddz && (v == 0u);
    else          even1 = even1 || (v == 1u);
  }
  const bool all_int01 = (__ballot(int01) == ~0ULL);
  const bool all_f01   = (__ballot(f01)   == ~0ULL);
  const bool all_oddz  = (__ballot(!oddz) == 0ULL);
  const bool any_even1 = (__ballot(even1) != 0ULL);
  int mflag = 0;
  if (all_int01)    mflag = (all_oddz && any_even1) ? 2 : 1;
  else if (all_f01) mflag = 3;

  // ---- lanes 0..5 of each wave compute their edge's scalar weight ----
  float wq = 0.f;
  int   sq = 0;
  if (lane < DEG_N) {
    const int e = r * DEG_N + lane;
    const int s = src[e];
    sq = s;
    const float dx = coords[2 * r]     - coords[2 * s];
    const float dy = coords[2 * r + 1] - coords[2 * s + 1];
    float b = 0.f;
#pragma unroll
    for (int m = 0; m < MF; ++m) {
      const float S = dx * W_reg[2 * m] + dy * W_reg[2 * m + 1];
      float sv, cv;
      __sincosf(S, &sv, &cv);
      b += cv * beta_cos[m] + sv * beta_sin[m];
    }
    bool mv;
    if (mflag == 1)      mv = ((const int*)mask_raw)[s] != 0;
    else if (mflag == 2) mv = ((const long long*)mask_raw)[s] != 0;
    else if (mflag == 3) mv = ((const float*)mask_raw)[s] != 0.f;
    else                 mv = ((const uint8_t*)mask_raw)[s] != 0;
    wq = mv ? fmaf(FB_COEF, b, 1.0f) : 0.f;
  }

  // ---- broadcast edge params (wave-uniform) ----
  const int   s0 = __shfl(sq, 0), s1 = __shfl(sq, 1), s2 = __shfl(sq, 2);
  const int   s3 = __shfl(sq, 3), s4 = __shfl(sq, 4), s5 = __shfl(sq, 5);
  const float w0 = __shfl(wq, 0), w1 = __shfl(wq, 1), w2 = __shfl(wq, 2);
  const float w3 = __shfl(wq, 3), w4 = __shfl(wq, 4), w5 = __shfl(wq, 5);

  const float* __restrict__ Wb = W_edges + (size_t)r * (DEG_N * D_DIM * D_DIM);

  // ---- issue all ACTIVE W loads first (nontemporal, evict-first) ----
  f4v wv0 = (f4v)(0.f), wv1 = (f4v)(0.f), wv2 = (f4v)(0.f);
  f4v wv3 = (f4v)(0.f), wv4 = (f4v)(0.f), wv5 = (f4v)(0.f);
#define WLOAD(kk, ww, vv)                                                    \
  if (ww != 0.f)                                                             \
    vv = __builtin_nontemporal_load(                                         \
        reinterpret_cast<const f4v*>(Wb + kk * (D_DIM * D_DIM) + t * 4));
  WLOAD(0, w0, wv0) WLOAD(1, w1, wv1) WLOAD(2, w2, wv2)
  WLOAD(3, w3, wv3) WLOAD(4, w4, wv4) WLOAD(5, w5, wv5)
#undef WLOAD

  // ---- accumulate: h-gather (L1/L2-resident) x streamed W ----
  float p = 0.f;
#define EDGE(ss, ww, vv)                                                     \
  if (ww != 0.f) {                                                           \
    const float4 hv = *reinterpret_cast<const float4*>(&H[ss * D_DIM + j0]); \
    p = fmaf(ww, vv.x * hv.x + vv.y * hv.y + vv.z * hv.z + vv.w * hv.w, p);  \
  }
  EDGE(s0, w0, wv0) EDGE(s1, w1, wv1) EDGE(s2, w2, wv2)
  EDGE(s3, w3, wv3) EDGE(s4, w4, wv4) EDGE(s5, w5, wv5)
#undef EDGE

  // ---- reduce across the 16 lanes owning each row ----
#pragma unroll
  for (int off = 1; off < 16; off <<= 1) p += __shfl_xor(p, off);

  // lanes 0,16,32,48 of each wave hold rows 4w..4w+3; compact into one
  // float4 store from lane 0 of the wave (unconditional: d_out is poisoned).
  const float p0 = __shfl(p, 0);
  const float p1 = __shfl(p, 16);
  const float p2 = __shfl(p, 32);
  const float p3 = __shfl(p, 48);
  if (lane == 0) {
    *reinterpret_cast<float4*>(&out[r * D_DIM + (q & ~3)]) =
        make_float4(p0, p1, p2, p3);
  }
}

extern "C" void kernel_launch(void* const* d_in, const int* in_sizes, int n_in,
                              void* d_out, int out_size, void* d_ws, size_t ws_size,
                              hipStream_t stream) {
  const float* H        = (const float*)d_in[0];
  const void*  mask     = d_in[1];
  const float* coords   = (const float*)d_in[2];
  const float* W_edges  = (const float*)d_in[3];
  const float* W_reg    = (const float*)d_in[4];
  const float* beta_cos = (const float*)d_in[5];
  const float* beta_sin = (const float*)d_in[6];
  const int*   src      = (const int*)d_in[7];
  // d_in[8] (dst) is structurally repeat(arange(R), 6); not needed.

  router_kernel<<<R_NUM, 1024, 0, stream>>>(H, mask, coords, W_edges, W_reg,
                                            beta_cos, beta_sin, src,
                                            (float*)d_out);
}